// Round 1
// baseline (669.735 us; speedup 1.0000x reference)
//
#include <hip/hip_runtime.h>

// SudokuLoss: B=65536 puzzles, G=9, C=10 classes, BS=3.
// v2: ONE THREAD PER CELL (was 3 threads/puzzle with 27 serial exec-masked
// bodies). puzzles/targets loads fully coalesced; only the 40B logits chunk
// is a conditional gather (~10% of lanes). Row/col/box digit-sums all go
// through LDS float atomics into per-puzzle group accumulators.
// Rationale: old kernel ran 3 waves/SIMD with a 27-deep serial divergent
// body chain -> latency-bound at ~25% of its memory roofline. This version
// gets latency hiding from occupancy (32 waves/CU) instead.

constexpr int kB   = 65536;
constexpr int PPB  = 6;            // puzzles per block
constexpr int TPB  = 512;          // threads per block (8 waves)
constexpr int CELLS = PPB * 81;    // 486 active lanes; 26 idle

__global__ __launch_bounds__(TPB) void sudoku_main(
    const float* __restrict__ logits,
    const int*   __restrict__ targets,
    const int*   __restrict__ puzzles,
    float*       __restrict__ ws)   // ws[0]=sum diff^2, ws[1]=sum ce, ws[2]=mask count
{
    // acc layout: [PPB puzzles][27 groups][10]
    //   groups 0..8 = rows, 9..17 = cols, 18..26 = boxes
    //   per group: idx 0..8 = class-c sums (c=1..9), idx 9 = mask count
    __shared__ float acc[PPB * 270];
    __shared__ float red[3][TPB / 64];

    const int tid = threadIdx.x;
    for (int i = tid; i < PPB * 270; i += TPB) acc[i] = 0.f;
    __syncthreads();

    const int pzbase = blockIdx.x * PPB;       // first puzzle of this block
    const int q      = tid / 81;               // puzzle within block (0..6)
    const int ci     = tid - q * 81;           // cell within puzzle (0..80)

    float ce = 0.f, mcnt = 0.f, diff2 = 0.f;

    if (q < PPB && (pzbase + q) < kB) {
        const int idx = pzbase * 81 + tid;     // == (pzbase+q)*81 + ci
        // both coalesced, independent, issued before any branch
        const int pz = puzzles[idx];
        const int tg = targets[idx];

        if (pz == 0) {
            const float* xp = logits + (size_t)idx * 10;   // 40B chunk, 8B-aligned
            float x[10];
            #pragma unroll
            for (int h = 0; h < 5; ++h) {
                const float2 v = *(const float2*)(xp + 2 * h);
                x[2 * h] = v.x; x[2 * h + 1] = v.y;
            }
            float mx = x[0];
            #pragma unroll
            for (int c = 1; c < 10; ++c) mx = fmaxf(mx, x[c]);
            float e[10];
            float S = 0.f;
            #pragma unroll
            for (int c = 0; c < 10; ++c) { e[c] = __expf(x[c] - mx); S += e[c]; }
            const float inv = 1.0f / S;

            float xt = x[0];
            #pragma unroll
            for (int c = 1; c < 10; ++c) xt = (tg == c) ? x[c] : xt;
            ce   = mx + __logf(S) - xt;        // -log_softmax(x)[tg]
            mcnt = 1.f;

            const int r  = ci / 9;
            const int j  = ci - r * 9;
            const int bx = (r / 3) * 3 + (j / 3);
            float* a = &acc[q * 270];
            float* ar = a + r * 10;            // row group
            float* ac = a + (9 + j) * 10;      // col group
            float* ab = a + (18 + bx) * 10;    // box group
            atomicAdd(ar + 9, 1.f);
            atomicAdd(ac + 9, 1.f);
            atomicAdd(ab + 9, 1.f);
            #pragma unroll
            for (int c = 1; c < 10; ++c) {
                const float w = e[c] * inv;
                atomicAdd(ar + (c - 1), w);
                atomicAdd(ac + (c - 1), w);
                atomicAdd(ab + (c - 1), w);
            }
        }
    }
    __syncthreads();

    // group MSE: 162 groups; out-of-range puzzles contribute 0 (acc stays 0)
    if (tid < PPB * 27) {
        const float* a = &acc[tid * 10];
        const float tm = a[9] * (1.f / 9.f);
        #pragma unroll
        for (int c = 0; c < 9; ++c) { const float d = a[c] - tm; diff2 += d * d; }
    }

    // wave (64-lane) reduction, then cross-wave via LDS
    #pragma unroll
    for (int off = 32; off > 0; off >>= 1) {
        diff2 += __shfl_down(diff2, off);
        ce    += __shfl_down(ce, off);
        mcnt  += __shfl_down(mcnt, off);
    }
    const int wave = tid >> 6;
    if ((tid & 63) == 0) { red[0][wave] = diff2; red[1][wave] = ce; red[2][wave] = mcnt; }
    __syncthreads();
    if (tid == 0) {
        float d = 0.f, c2 = 0.f, m = 0.f;
        #pragma unroll
        for (int w = 0; w < TPB / 64; ++w) { d += red[0][w]; c2 += red[1][w]; m += red[2][w]; }
        atomicAdd(&ws[0], d);
        atomicAdd(&ws[1], c2);
        atomicAdd(&ws[2], m);
    }
}

__global__ void sudoku_final(const float* __restrict__ ws, float* __restrict__ out)
{
    const float diff2   = ws[0];
    const float ce_sum  = ws[1];
    const float msum    = ws[2];
    const float ce_loss = ce_sum / (msum + 1e-8f);
    // each of row/col/box loss = sum(diff^2)/(B*9); constraint = sum/27
    const float constraint = diff2 / ((float)kB * 9.f * 27.f);
    out[0] = ce_loss + 0.1f * constraint;
    out[1] = ce_loss;
    out[2] = constraint;
}

extern "C" void kernel_launch(void* const* d_in, const int* in_sizes, int n_in,
                              void* d_out, int out_size, void* d_ws, size_t ws_size,
                              hipStream_t stream)
{
    const float* logits  = (const float*)d_in[0];
    const int*   targets = (const int*)d_in[1];
    const int*   puzzles = (const int*)d_in[2];
    float* ws  = (float*)d_ws;
    float* out = (float*)d_out;

    hipMemsetAsync(d_ws, 0, 3 * sizeof(float), stream);

    const int blocks = (kB + PPB - 1) / PPB;   // 10923
    sudoku_main<<<blocks, TPB, 0, stream>>>(logits, targets, puzzles, ws);
    sudoku_final<<<1, 1, 0, stream>>>(ws, out);
}

// Round 2
// 364.927 us; speedup vs baseline: 1.8353x; 1.8353x over previous
//
#include <hip/hip_runtime.h>

// SudokuLoss: B=65536 puzzles, G=9, C=10 classes, BS=3.
// v3: one thread per cell (v2 structure) + FIXED the global-atomic
// serialization that made v2 10x slower than it should be.
// v2 post-mortem: 10923 blocks x 3 device-scope atomicAdds to the SAME
// 12B of ws = 98K serialized same-line RMWs (~4ns each ~= 393us) -- the
// kernel showed HBM 1.7%, VALU 7%, i.e. nothing busy, pure serialization.
// v3 spreads block partials across 256 cache-line-padded slots
// (blockIdx & 255, 64B stride), cutting same-line contention by ~256x.
// sudoku_final (one wave) reduces the slots.

constexpr int kB    = 65536;
constexpr int PPB   = 6;            // puzzles per block
constexpr int TPB   = 512;          // threads per block (8 waves)
constexpr int NSLOT = 256;          // global accumulation slots
constexpr int SLOT_STRIDE = 16;     // floats per slot (64B = one cache line)

__global__ __launch_bounds__(TPB) void sudoku_main(
    const float* __restrict__ logits,
    const int*   __restrict__ targets,
    const int*   __restrict__ puzzles,
    float*       __restrict__ ws)   // ws: [NSLOT][16] floats; per slot: [0]=diff2 [1]=ce [2]=mcnt
{
    // acc layout: [PPB puzzles][27 groups][10]
    //   groups 0..8 = rows, 9..17 = cols, 18..26 = boxes
    //   per group: idx 0..8 = class-c sums (c=1..9), idx 9 = mask count
    __shared__ float acc[PPB * 270];
    __shared__ float red[3][TPB / 64];

    const int tid = threadIdx.x;
    for (int i = tid; i < PPB * 270; i += TPB) acc[i] = 0.f;
    __syncthreads();

    const int pzbase = blockIdx.x * PPB;       // first puzzle of this block
    const int q      = tid / 81;               // puzzle within block (0..6)
    const int ci     = tid - q * 81;           // cell within puzzle (0..80)

    float ce = 0.f, mcnt = 0.f, diff2 = 0.f;

    if (q < PPB && (pzbase + q) < kB) {
        const int idx = pzbase * 81 + tid;     // == (pzbase+q)*81 + ci
        // both coalesced, independent, issued before any branch
        const int pz = puzzles[idx];
        const int tg = targets[idx];

        if (pz == 0) {
            const float* xp = logits + (size_t)idx * 10;   // 40B chunk, 8B-aligned
            float x[10];
            #pragma unroll
            for (int h = 0; h < 5; ++h) {
                const float2 v = *(const float2*)(xp + 2 * h);
                x[2 * h] = v.x; x[2 * h + 1] = v.y;
            }
            float mx = x[0];
            #pragma unroll
            for (int c = 1; c < 10; ++c) mx = fmaxf(mx, x[c]);
            float e[10];
            float S = 0.f;
            #pragma unroll
            for (int c = 0; c < 10; ++c) { e[c] = __expf(x[c] - mx); S += e[c]; }
            const float inv = 1.0f / S;

            float xt = x[0];
            #pragma unroll
            for (int c = 1; c < 10; ++c) xt = (tg == c) ? x[c] : xt;
            ce   = mx + __logf(S) - xt;        // -log_softmax(x)[tg]
            mcnt = 1.f;

            const int r  = ci / 9;
            const int j  = ci - r * 9;
            const int bx = (r / 3) * 3 + (j / 3);
            float* a = &acc[q * 270];
            float* ar = a + r * 10;            // row group
            float* ac = a + (9 + j) * 10;      // col group
            float* ab = a + (18 + bx) * 10;    // box group
            atomicAdd(ar + 9, 1.f);
            atomicAdd(ac + 9, 1.f);
            atomicAdd(ab + 9, 1.f);
            #pragma unroll
            for (int c = 1; c < 10; ++c) {
                const float w = e[c] * inv;
                atomicAdd(ar + (c - 1), w);
                atomicAdd(ac + (c - 1), w);
                atomicAdd(ab + (c - 1), w);
            }
        }
    }
    __syncthreads();

    // group MSE: 162 groups; out-of-range puzzles contribute 0 (acc stays 0)
    if (tid < PPB * 27) {
        const float* a = &acc[tid * 10];
        const float tm = a[9] * (1.f / 9.f);
        #pragma unroll
        for (int c = 0; c < 9; ++c) { const float d = a[c] - tm; diff2 += d * d; }
    }

    // wave (64-lane) reduction, then cross-wave via LDS
    #pragma unroll
    for (int off = 32; off > 0; off >>= 1) {
        diff2 += __shfl_down(diff2, off);
        ce    += __shfl_down(ce, off);
        mcnt  += __shfl_down(mcnt, off);
    }
    const int wave = tid >> 6;
    if ((tid & 63) == 0) { red[0][wave] = diff2; red[1][wave] = ce; red[2][wave] = mcnt; }
    __syncthreads();
    if (tid == 0) {
        float d = 0.f, c2 = 0.f, m = 0.f;
        #pragma unroll
        for (int w = 0; w < TPB / 64; ++w) { d += red[0][w]; c2 += red[1][w]; m += red[2][w]; }
        float* slot = ws + (size_t)(blockIdx.x & (NSLOT - 1)) * SLOT_STRIDE;
        atomicAdd(&slot[0], d);
        atomicAdd(&slot[1], c2);
        atomicAdd(&slot[2], m);
    }
}

__global__ void sudoku_final(const float* __restrict__ ws, float* __restrict__ out)
{
    // one wave: each lane sums 4 slots, then shuffle-reduce
    const int t = threadIdx.x;
    float d = 0.f, c2 = 0.f, m = 0.f;
    for (int s = t; s < NSLOT; s += 64) {
        const float* sl = ws + (size_t)s * SLOT_STRIDE;
        d += sl[0]; c2 += sl[1]; m += sl[2];
    }
    #pragma unroll
    for (int off = 32; off > 0; off >>= 1) {
        d  += __shfl_down(d, off);
        c2 += __shfl_down(c2, off);
        m  += __shfl_down(m, off);
    }
    if (t == 0) {
        const float ce_loss = c2 / (m + 1e-8f);
        // each of row/col/box loss = sum(diff^2)/(B*9); constraint = sum/27
        const float constraint = d / ((float)kB * 9.f * 27.f);
        out[0] = ce_loss + 0.1f * constraint;
        out[1] = ce_loss;
        out[2] = constraint;
    }
}

extern "C" void kernel_launch(void* const* d_in, const int* in_sizes, int n_in,
                              void* d_out, int out_size, void* d_ws, size_t ws_size,
                              hipStream_t stream)
{
    const float* logits  = (const float*)d_in[0];
    const int*   targets = (const int*)d_in[1];
    const int*   puzzles = (const int*)d_in[2];
    float* ws  = (float*)d_ws;
    float* out = (float*)d_out;

    hipMemsetAsync(d_ws, 0, NSLOT * SLOT_STRIDE * sizeof(float), stream);

    const int blocks = (kB + PPB - 1) / PPB;   // 10923
    sudoku_main<<<blocks, TPB, 0, stream>>>(logits, targets, puzzles, ws);
    sudoku_final<<<1, 64, 0, stream>>>(ws, out);
}

// Round 3
// 351.703 us; speedup vs baseline: 1.9043x; 1.0376x over previous
//
#include <hip/hip_runtime.h>

// SudokuLoss: B=65536 puzzles, G=9, C=10 classes, BS=3.
// v4: one thread per cell, UNCONDITIONAL coalesced logits streaming,
// ZERO LDS atomics.
// v3 post-mortem: 128.6us main with HBM at 7% and VALU ~24% -- the cost was
// (a) 30 LDS atomic-RMWs per masked wave (~2.6M ds_atomic instrs) and
// (b) divergent exec-masked 40B gathers paying full HBM latency.
// Arithmetic: streaming ALL inputs dense is only 254 MB = 40us at 6.3TB/s,
// BELOW what the "skip 90% of logits" versions achieved (65/128us). So v4
// streams everything with full-lane coalesced loads, computes softmax on
// every lane (VALU ~4us total), and aggregates via a two-phase LDS scheme:
//   phase 1: each cell writes [mask, w1..w9] to its private 48B LDS slot
//            (conflict-free b128 writes, no atomics, no init loop)
//   phase 2: each (puzzle,group) pair -> one thread; 9 cells x aligned
//            vector reads, MSE in registers. Every LDS word has exactly
//            one writer and deterministic readers.

constexpr int kB    = 65536;
constexpr int PPB   = 6;            // puzzles per block
constexpr int TPB   = 512;          // threads per block (8 waves)
constexpr int NSLOT = 256;          // global accumulation slots
constexpr int SLOT_STRIDE = 16;     // floats per slot (64B = one cache line)
constexpr int CSTRIDE = 12;         // floats per cell slot in LDS (48B, 16B-aligned)

__global__ __launch_bounds__(TPB) void sudoku_main(
    const float* __restrict__ logits,
    const int*   __restrict__ targets,
    const int*   __restrict__ puzzles,
    float*       __restrict__ ws)   // ws: [NSLOT][16]; per slot: [0]=diff2 [1]=ce [2]=mcnt
{
    // per-cell slots: [0]=mask, [1..9]=masked softmax probs (classes 1..9)
    __shared__ __align__(16) float probs[TPB * CSTRIDE];   // 24576 B
    __shared__ float red[3][TPB / 64];

    const int tid    = threadIdx.x;
    const int pzbase = blockIdx.x * PPB;
    const int q      = tid / 81;               // puzzle within block (0..6)

    float ce = 0.f, mcnt = 0.f;
    float wv[10];
    #pragma unroll
    for (int c = 0; c < 10; ++c) wv[c] = 0.f;

    const bool active = (q < PPB) && (pzbase + q < kB);
    if (active) {
        const int idx = pzbase * 81 + tid;     // == (pzbase+q)*81 + ci
        const int pz = puzzles[idx];
        const int tg = targets[idx];

        // unconditional 40B load: lanes consecutive -> dense, coalesced
        const float* xp = logits + (size_t)idx * 10;
        float x[10];
        #pragma unroll
        for (int h = 0; h < 5; ++h) {
            const float2 v = *(const float2*)(xp + 2 * h);
            x[2 * h] = v.x; x[2 * h + 1] = v.y;
        }
        float mx = x[0];
        #pragma unroll
        for (int c = 1; c < 10; ++c) mx = fmaxf(mx, x[c]);
        float e[10];
        float S = 0.f;
        #pragma unroll
        for (int c = 0; c < 10; ++c) { e[c] = __expf(x[c] - mx); S += e[c]; }
        const float inv = 1.0f / S;

        if (pz == 0) {
            float xt = x[0];
            #pragma unroll
            for (int c = 1; c < 10; ++c) xt = (tg == c) ? x[c] : xt;
            ce   = mx + __logf(S) - xt;        // -log_softmax(x)[tg]
            mcnt = 1.f;
            wv[0] = 1.f;
            #pragma unroll
            for (int c = 1; c < 10; ++c) wv[c] = e[c] * inv;
        }
    }
    // every thread (incl. inactive) writes its slot: zeros where unmasked/OOB
    {
        float* dst = &probs[tid * CSTRIDE];
        *(float4*)(dst + 0) = make_float4(wv[0], wv[1], wv[2], wv[3]);
        *(float4*)(dst + 4) = make_float4(wv[4], wv[5], wv[6], wv[7]);
        *(float2*)(dst + 8) = make_float2(wv[8], wv[9]);
    }
    __syncthreads();

    // phase 2: one thread per (puzzle, group); group-major for wave uniformity
    //   t in [0,54)    : rows  (q2 = t/9,       r = t%9)
    //   t in [54,108)  : cols  (q2 = (t-54)/9,  j = (t-54)%9)
    //   t in [108,162) : boxes (q2 = (t-108)/9, b = (t-108)%9)
    float diff2 = 0.f;
    if (tid < PPB * 27) {
        float s[10];
        #pragma unroll
        for (int c = 0; c < 10; ++c) s[c] = 0.f;

        if (tid < PPB * 9) {
            const int q2 = tid / 9, r = tid - q2 * 9;
            const float* base = &probs[(q2 * 81 + r * 9) * CSTRIDE];
            #pragma unroll
            for (int i = 0; i < 9; ++i) {
                const float* cell = base + i * CSTRIDE;
                const float4 a = *(const float4*)(cell + 0);
                const float4 b = *(const float4*)(cell + 4);
                const float2 c2 = *(const float2*)(cell + 8);
                s[0]+=a.x; s[1]+=a.y; s[2]+=a.z; s[3]+=a.w;
                s[4]+=b.x; s[5]+=b.y; s[6]+=b.z; s[7]+=b.w;
                s[8]+=c2.x; s[9]+=c2.y;
            }
        } else if (tid < PPB * 18) {
            const int u = tid - PPB * 9;
            const int q2 = u / 9, j = u - q2 * 9;
            const float* base = &probs[(q2 * 81 + j) * CSTRIDE];
            #pragma unroll
            for (int i = 0; i < 9; ++i) {
                const float* cell = base + i * (9 * CSTRIDE);
                const float4 a = *(const float4*)(cell + 0);
                const float4 b = *(const float4*)(cell + 4);
                const float2 c2 = *(const float2*)(cell + 8);
                s[0]+=a.x; s[1]+=a.y; s[2]+=a.z; s[3]+=a.w;
                s[4]+=b.x; s[5]+=b.y; s[6]+=b.z; s[7]+=b.w;
                s[8]+=c2.x; s[9]+=c2.y;
            }
        } else {
            const int u = tid - PPB * 18;
            const int q2 = u / 9, b = u - q2 * 9;
            const int br = b / 3, bc = b - br * 3;
            const float* base = &probs[(q2 * 81 + br * 27 + bc * 3) * CSTRIDE];
            #pragma unroll
            for (int dr = 0; dr < 3; ++dr) {
                #pragma unroll
                for (int dc = 0; dc < 3; ++dc) {
                    const float* cell = base + (dr * 9 + dc) * CSTRIDE;
                    const float4 a = *(const float4*)(cell + 0);
                    const float4 bb = *(const float4*)(cell + 4);
                    const float2 c2 = *(const float2*)(cell + 8);
                    s[0]+=a.x; s[1]+=a.y; s[2]+=a.z; s[3]+=a.w;
                    s[4]+=bb.x; s[5]+=bb.y; s[6]+=bb.z; s[7]+=bb.w;
                    s[8]+=c2.x; s[9]+=c2.y;
                }
            }
        }
        const float tm = s[0] * (1.f / 9.f);
        #pragma unroll
        for (int c = 1; c < 10; ++c) { const float d = s[c] - tm; diff2 += d * d; }
    }

    // wave (64-lane) reduction, then cross-wave via LDS
    #pragma unroll
    for (int off = 32; off > 0; off >>= 1) {
        diff2 += __shfl_down(diff2, off);
        ce    += __shfl_down(ce, off);
        mcnt  += __shfl_down(mcnt, off);
    }
    const int wave = tid >> 6;
    if ((tid & 63) == 0) { red[0][wave] = diff2; red[1][wave] = ce; red[2][wave] = mcnt; }
    __syncthreads();
    if (tid == 0) {
        float d = 0.f, c2 = 0.f, m = 0.f;
        #pragma unroll
        for (int w = 0; w < TPB / 64; ++w) { d += red[0][w]; c2 += red[1][w]; m += red[2][w]; }
        float* slot = ws + (size_t)(blockIdx.x & (NSLOT - 1)) * SLOT_STRIDE;
        atomicAdd(&slot[0], d);
        atomicAdd(&slot[1], c2);
        atomicAdd(&slot[2], m);
    }
}

__global__ void sudoku_final(const float* __restrict__ ws, float* __restrict__ out)
{
    // one wave: each lane sums 4 slots, then shuffle-reduce
    const int t = threadIdx.x;
    float d = 0.f, c2 = 0.f, m = 0.f;
    for (int s = t; s < NSLOT; s += 64) {
        const float* sl = ws + (size_t)s * SLOT_STRIDE;
        d += sl[0]; c2 += sl[1]; m += sl[2];
    }
    #pragma unroll
    for (int off = 32; off > 0; off >>= 1) {
        d  += __shfl_down(d, off);
        c2 += __shfl_down(c2, off);
        m  += __shfl_down(m, off);
    }
    if (t == 0) {
        const float ce_loss = c2 / (m + 1e-8f);
        // each of row/col/box loss = sum(diff^2)/(B*9); constraint = sum/27
        const float constraint = d / ((float)kB * 9.f * 27.f);
        out[0] = ce_loss + 0.1f * constraint;
        out[1] = ce_loss;
        out[2] = constraint;
    }
}

extern "C" void kernel_launch(void* const* d_in, const int* in_sizes, int n_in,
                              void* d_out, int out_size, void* d_ws, size_t ws_size,
                              hipStream_t stream)
{
    const float* logits  = (const float*)d_in[0];
    const int*   targets = (const int*)d_in[1];
    const int*   puzzles = (const int*)d_in[2];
    float* ws  = (float*)d_ws;
    float* out = (float*)d_out;

    hipMemsetAsync(d_ws, 0, NSLOT * SLOT_STRIDE * sizeof(float), stream);

    const int blocks = (kB + PPB - 1) / PPB;   // 10923
    sudoku_main<<<blocks, TPB, 0, stream>>>(logits, targets, puzzles, ws);
    sudoku_final<<<1, 64, 0, stream>>>(ws, out);
}